// Round 11
// baseline (442.329 us; speedup 1.0000x reference)
//
#include <hip/hip_runtime.h>
#include <hip/hip_fp16.h>
#include <math.h>

#define NPTS 6144
#define CH   128

typedef __attribute__((ext_vector_type(8))) short short8;
typedef __attribute__((ext_vector_type(4))) float f32x4;
typedef __attribute__((ext_vector_type(2))) float f32x2;
typedef __attribute__((ext_vector_type(4))) int   i32x4;

__device__ inline ushort f2bf(float f) {
  union { float f; unsigned u; } v; v.f = f;
  unsigned u = v.u;
  u += 0x7fff + ((u >> 16) & 1);   // round-to-nearest-even
  return (ushort)(u >> 16);
}

__device__ inline f32x2 splat2(float x) { return (f32x2){x, x}; }

__device__ inline float fsqrt(float x) {
  float r; asm("v_sqrt_f32 %0, %1" : "=v"(r) : "v"(x)); return r;
}
__device__ inline float fexp2(float x) {
  float r; asm("v_exp_f32 %0, %1" : "=v"(r) : "v"(x)); return r;
}
__device__ inline unsigned cvtpk(float a, float b) {
  unsigned r;
  asm("v_cvt_pk_bf16_f32 %0, %1, %2" : "=v"(r) : "v"(a), "v"(b));
  return r;
}
__device__ inline float h2f(ushort h) {
  float r; asm("v_cvt_f32_f16 %0, %1" : "=v"(r) : "v"((unsigned)h)); return r;
}
__device__ inline ushort f2h(float f) {
  unsigned r; asm("v_cvt_f16_f32 %0, %1" : "=v"(r) : "v"(f)); return (ushort)r;
}

// ---------------------------------------------------------------------------
// Kernel 0 (optional): precompute geo as fp16 [NPTS][NPTS].  Layer-invariant.
// geo = max(1 - (dref-dsrc)^2/sigma^2, 0); (dref-dsrc)^2 = d2r+d2s-2*sqrt(d2r*d2s).
// ---------------------------------------------------------------------------
__global__ __launch_bounds__(256) void k_geo(
    const float* __restrict__ refp, const float* __restrict__ srcp,
    ushort* __restrict__ geo) {
  const int tid = threadIdx.x;
  const int q = blockIdx.x * 64 + (tid >> 2);
  const int k0 = blockIdx.y * 256;
  __shared__ float kco[256][8];
  {
    int k = k0 + tid;
    float rx = refp[k * 3], ry = refp[k * 3 + 1], rz = refp[k * 3 + 2];
    float sx = srcp[k * 3], sy = srcp[k * 3 + 1], sz = srcp[k * 3 + 2];
    kco[tid][0] = rx; kco[tid][1] = ry; kco[tid][2] = rz;
    kco[tid][3] = rx * rx + ry * ry + rz * rz;
    kco[tid][4] = sx; kco[tid][5] = sy; kco[tid][6] = sz;
    kco[tid][7] = sx * sx + sy * sy + sz * sz;
  }
  const float rqx = refp[q * 3], rqy = refp[q * 3 + 1], rqz = refp[q * 3 + 2];
  const float sqx = srcp[q * 3], sqy = srcp[q * 3 + 1], sqz = srcp[q * 3 + 2];
  const float nrq = rqx * rqx + rqy * rqy + rqz * rqz;
  const float nsq = sqx * sqx + sqy * sqy + sqz * sqz;
  __syncthreads();
  const float invs2 = 1.0f / (0.3f * 0.3f);
  const int kloc = (tid & 3) * 64;
  for (int i = 0; i < 64; i += 4) {
    ushort4 outv;
    ushort* po = (ushort*)&outv;
    #pragma unroll
    for (int j = 0; j < 4; j++) {
      const float* kc_ = kco[kloc + i + j];
      float d2r = fmaxf(nrq + kc_[3] -
                        2.0f * (rqx * kc_[0] + rqy * kc_[1] + rqz * kc_[2]), 0.f);
      float d2s = fmaxf(nsq + kc_[7] -
                        2.0f * (sqx * kc_[4] + sqy * kc_[5] + sqz * kc_[6]), 0.f);
      float dd2 = fmaxf(d2r + d2s - 2.0f * fsqrt(d2r * d2s), 0.f);
      float gg = fmaxf(fmaf(dd2, -invs2, 1.0f), 0.f);
      po[j] = f2h(gg);
    }
    *(ushort4*)(geo + (size_t)q * NPTS + k0 + kloc + i) = outv;
  }
}

// ---------------------------------------------------------------------------
// Kernel 1: embedding  feat = [corr_feat, centered(kp)] @ W_in + b_in
// ---------------------------------------------------------------------------
__global__ __launch_bounds__(128) void k_embed(
    const float* __restrict__ refp, const float* __restrict__ srcp,
    const float* __restrict__ cf, const float* __restrict__ Win,
    const float* __restrict__ bin, float* __restrict__ out) {
  const int row = blockIdx.x, j = threadIdx.x;
  __shared__ float inb[12];
  __shared__ float mkp;
  if (j < 6)       inb[j] = cf[row * 6 + j];
  else if (j < 9)  inb[j] = refp[row * 3 + (j - 6)];
  else if (j < 12) inb[j] = srcp[row * 3 + (j - 9)];
  __syncthreads();
  if (j == 0) {
    float s = inb[6] + inb[7] + inb[8] + inb[9] + inb[10] + inb[11];
    mkp = s * (1.0f / 6.0f);
  }
  __syncthreads();
  float acc = bin[j];
  #pragma unroll
  for (int kk = 0; kk < 12; kk++) {
    float x = inb[kk] - (kk >= 6 ? mkp : 0.0f);
    acc = fmaf(x, Win[kk * CH + j], acc);
  }
  out[row * CH + j] = acc;
}

// ---------------------------------------------------------------------------
// Kernel 2: fused UnaryBlock (linear+LN+leaky) + QKV projection, 4 rows/block
// (r6-proven: 1536 blocks = parallelism-bound optimum for these tiny GEMMs).
// V written transposed AND chunk-permuted.
// ---------------------------------------------------------------------------
__global__ __launch_bounds__(128) void k_mlp_qkv(
    const float* __restrict__ X, const float* __restrict__ W,
    const float* __restrict__ b, const float* __restrict__ g,
    const float* __restrict__ beta,
    const float* __restrict__ Wq, const float* __restrict__ bq,
    const float* __restrict__ Wk, const float* __restrict__ bk,
    const float* __restrict__ Wv, const float* __restrict__ bv,
    float* __restrict__ T, ushort* __restrict__ Q, ushort* __restrict__ K,
    ushort* __restrict__ Vt) {
  const int j = threadIdx.x;
  const int r0 = blockIdx.x * 4;
  __shared__ float xs[4][CH];
  __shared__ float hs[4][CH];
  __shared__ float red[2][4];
  #pragma unroll
  for (int r = 0; r < 4; r++) xs[r][j] = X[(r0 + r) * CH + j];
  __syncthreads();

  float acc[4];
  const float bj = b[j];
  #pragma unroll
  for (int r = 0; r < 4; r++) acc[r] = bj;
  for (int kk = 0; kk < CH; kk++) {
    float wv_ = W[kk * CH + j];
    #pragma unroll
    for (int r = 0; r < 4; r++) acc[r] = fmaf(xs[r][kk], wv_, acc[r]);
  }
  const int wv2 = j >> 6, ln = j & 63;
  float sum[4];
  #pragma unroll
  for (int r = 0; r < 4; r++) sum[r] = acc[r];
  #pragma unroll
  for (int o = 32; o; o >>= 1) {
    #pragma unroll
    for (int r = 0; r < 4; r++) sum[r] += __shfl_xor(sum[r], o);
  }
  if (ln == 0) {
    #pragma unroll
    for (int r = 0; r < 4; r++) red[wv2][r] = sum[r];
  }
  __syncthreads();
  float dv[4];
  #pragma unroll
  for (int r = 0; r < 4; r++) {
    float mean = (red[0][r] + red[1][r]) * (1.0f / 128.0f);
    dv[r] = acc[r] - mean;
    sum[r] = dv[r] * dv[r];
  }
  #pragma unroll
  for (int o = 32; o; o >>= 1) {
    #pragma unroll
    for (int r = 0; r < 4; r++) sum[r] += __shfl_xor(sum[r], o);
  }
  __syncthreads();
  if (ln == 0) {
    #pragma unroll
    for (int r = 0; r < 4; r++) red[wv2][r] = sum[r];
  }
  __syncthreads();
  const float gj = g[j], betaj = beta[j];
  #pragma unroll
  for (int r = 0; r < 4; r++) {
    float var = (red[0][r] + red[1][r]) * (1.0f / 128.0f);
    float y = dv[r] * rsqrtf(var + 1e-5f) * gj + betaj;
    y = (y > 0.0f) ? y : 0.1f * y;
    T[(r0 + r) * CH + j] = y;
    hs[r][j] = y;
  }
  __syncthreads();

  float aq[4], ak[4], av[4];
  const float bqj = bq[j], bkj = bk[j], bvj = bv[j];
  #pragma unroll
  for (int r = 0; r < 4; r++) { aq[r] = bqj; ak[r] = bkj; av[r] = bvj; }
  for (int kk = 0; kk < CH; kk++) {
    float wq = Wq[kk * CH + j], wk = Wk[kk * CH + j], wv_ = Wv[kk * CH + j];
    #pragma unroll
    for (int r = 0; r < 4; r++) {
      float x = hs[r][kk];
      aq[r] = fmaf(x, wq, aq[r]);
      ak[r] = fmaf(x, wk, ak[r]);
      av[r] = fmaf(x, wv_, av[r]);
    }
  }
  const float scale = 0.12751879524143007f;  // 1/sqrt(128) * log2(e)
  #pragma unroll
  for (int r = 0; r < 4; r++) {
    Q[(r0 + r) * CH + j] = f2bf(aq[r] * scale);
    K[(r0 + r) * CH + j] = f2bf(ak[r]);
  }
  ushort4 vp;
  vp.x = f2bf(av[0]); vp.y = f2bf(av[1]); vp.z = f2bf(av[2]); vp.w = f2bf(av[3]);
  const int w0 = r0 & 63;
  const int pos = (r0 & ~63) + 32 * ((w0 >> 5) & 1) + 8 * ((w0 >> 2) & 3) +
                  4 * ((w0 >> 4) & 1);
  *(ushort4*)(Vt + (size_t)j * NPTS + pos) = vp;
}

// ---------------------------------------------------------------------------
// Kernel 3: MFMA flash attention, KV-split. 512 thr = 8 waves, 128 q-rows.
// Register-staged, SINGLE-buffered Ks and Vs (reg prefetch makes double
// buffering redundant under the 2-barrier schedule) -> 32.8 KB LDS.
// GEO=1: geo read from precomputed fp16 table (prefetched to regs);
// GEO=0: inline geo from LDS-staged coords (fallback when ws too small).
// ---------------------------------------------------------------------------
template <int GEO>
__global__ __launch_bounds__(512, 4) void k_attn_mfma(
    const ushort* __restrict__ Q, const ushort* __restrict__ K,
    const ushort* __restrict__ Vt, const ushort* __restrict__ geo,
    const float* __restrict__ refp, const float* __restrict__ srcp,
    float* __restrict__ Opart, float* __restrict__ ML, int ntiles) {
  const int tid = threadIdx.x;
  const int w = tid >> 6, ln = tid & 63;
  const int l15 = ln & 15, g = ln >> 4;
  const int row0 = blockIdx.x * 128;
  const int seg = blockIdx.y;
  const int t0 = seg * ntiles;

  __shared__ ushort Ks[64][128];   // chunk c of row r stored at c^(r&7)
  __shared__ ushort Vs[128][64];   // chunk c of ch row stored at c^(ch&7)
  __shared__ float cs2[6][(GEO == 0) ? 64 : 4];

  const int krow = tid >> 4;
  const int kc   = tid & 15;
  const int kofs = krow * 256 + ((kc ^ (krow & 7)) << 4);
  const int vch  = tid >> 3;
  const int vc   = tid & 7;
  const int vofs = vch * 128 + ((vc ^ (vch & 7)) << 4);

  short8 kreg0, kreg1, vreg0, vreg1;
  float cr[6];
  const int qrow = row0 + 16 * w + l15;

  auto issue = [&](int t) {
    const ushort* kp = K + (size_t)(t * 64 + krow) * CH + kc * 8;
    kreg0 = *(const short8*)kp;
    kreg1 = *(const short8*)(kp + (size_t)32 * CH);
    const ushort* vp = Vt + (size_t)vch * NPTS + t * 64 + vc * 8;
    vreg0 = *(const short8*)vp;
    vreg1 = *(const short8*)(vp + (size_t)64 * NPTS);
    if constexpr (GEO == 0) {
      if (tid < 64) {
        int gj = t * 64 + tid;
        cr[0] = refp[gj * 3]; cr[1] = refp[gj * 3 + 1]; cr[2] = refp[gj * 3 + 2];
        cr[3] = srcp[gj * 3]; cr[4] = srcp[gj * 3 + 1]; cr[5] = srcp[gj * 3 + 2];
      }
    }
  };
  ushort4 gcur[4], gnxt[4];
  auto issueG = [&](int t, ushort4* gg) {
    const ushort* gp = geo + (size_t)qrow * NPTS + t * 64 + 4 * g;
    #pragma unroll
    for (int nb = 0; nb < 4; nb++) gg[nb] = *(const ushort4*)(gp + 16 * nb);
  };

  short8 qf[4];
  {
    const ushort* qp = Q + (size_t)qrow * CH + 8 * g;
    #pragma unroll
    for (int ks = 0; ks < 4; ks++) qf[ks] = *(const short8*)(qp + 32 * ks);
  }
  float rq0 = 0, rq1 = 0, rq2 = 0, sq0 = 0, sq1 = 0, sq2 = 0;
  if constexpr (GEO == 0) {
    rq0 = refp[qrow * 3]; rq1 = refp[qrow * 3 + 1]; rq2 = refp[qrow * 3 + 2];
    sq0 = srcp[qrow * 3]; sq1 = srcp[qrow * 3 + 1]; sq2 = srcp[qrow * 3 + 2];
  }

  f32x4 oacc[8];
  #pragma unroll
  for (int n = 0; n < 8; n++) oacc[n] = (f32x4){0.f, 0.f, 0.f, 0.f};
  float m = -1e30f, l = 0.0f;
  const float invs2 = 1.0f / (0.3f * 0.3f);

  // ---- prologue: stage tile t0 ----
  issue(t0);
  if constexpr (GEO == 1) issueG(t0, gcur);
  *(short8*)((char*)&Ks[0][0] + kofs) = kreg0;
  *(short8*)((char*)&Ks[0][0] + kofs + 32 * 256) = kreg1;
  *(short8*)((char*)&Vs[0][0] + vofs) = vreg0;
  *(short8*)((char*)&Vs[0][0] + vofs + 64 * 128) = vreg1;
  if constexpr (GEO == 0) {
    if (tid < 64) {
      #pragma unroll
      for (int d = 0; d < 6; d++) cs2[d][tid] = cr[d];
    }
  }
  __syncthreads();

  for (int tt = 0; tt < ntiles; tt++) {
    if (tt + 1 < ntiles) {
      issue(t0 + tt + 1);
      if constexpr (GEO == 1) issueG(t0 + tt + 1, gnxt);
    }

    // ---- S^T = K @ Q^T : lane holds S[q=l15][key=16nb+4g+r] ----
    f32x4 acc[4];
    #pragma unroll
    for (int nb = 0; nb < 4; nb++) acc[nb] = (f32x4){0.f, 0.f, 0.f, 0.f};
    __builtin_amdgcn_s_setprio(1);
    #pragma unroll
    for (int ks = 0; ks < 4; ks++) {
      #pragma unroll
      for (int nb = 0; nb < 4; nb++) {
        const char* src = (const char*)&Ks[0][0] + (16 * nb + l15) * 256 +
                          (((4 * ks + g) ^ (l15 & 7)) << 4);
        short8 af = *(const short8*)src;
        acc[nb] = __builtin_amdgcn_mfma_f32_16x16x32_bf16(af, qf[ks], acc[nb], 0, 0, 0);
      }
    }
    __builtin_amdgcn_s_setprio(0);

    // ---- geo * S (log2 domain) ----
    float plog[4][4];
    if constexpr (GEO == 1) {
      #pragma unroll
      for (int nb = 0; nb < 4; nb++) {
        plog[nb][0] = h2f(gcur[nb].x) * acc[nb][0];
        plog[nb][1] = h2f(gcur[nb].y) * acc[nb][1];
        plog[nb][2] = h2f(gcur[nb].z) * acc[nb][2];
        plog[nb][3] = h2f(gcur[nb].w) * acc[nb][3];
      }
    } else {
      #pragma unroll
      for (int nb = 0; nb < 4; nb++) {
        const int kb = 16 * nb + 4 * g;
        #pragma unroll
        for (int pp = 0; pp < 2; pp++) {
          const int k2 = kb + 2 * pp;
          f32x2 cx = *(const f32x2*)&cs2[0][k2];
          f32x2 cy = *(const f32x2*)&cs2[1][k2];
          f32x2 cz = *(const f32x2*)&cs2[2][k2];
          f32x2 dx = splat2(rq0) - cx, dy = splat2(rq1) - cy, dz = splat2(rq2) - cz;
          f32x2 d2r = dx * dx + dy * dy + dz * dz;
          cx = *(const f32x2*)&cs2[3][k2];
          cy = *(const f32x2*)&cs2[4][k2];
          cz = *(const f32x2*)&cs2[5][k2];
          dx = splat2(sq0) - cx; dy = splat2(sq1) - cy; dz = splat2(sq2) - cz;
          f32x2 d2s = dx * dx + dy * dy + dz * dz;
          f32x2 prod = d2r * d2s;
          f32x2 sum2 = d2r + d2s;
          float s0 = fsqrt(prod[0]), s1 = fsqrt(prod[1]);
          float dd20 = fmaf(-2.0f, s0, sum2[0]);
          float dd21 = fmaf(-2.0f, s1, sum2[1]);
          float gg0 = fmaxf(fmaf(dd20, -invs2, 1.0f), 0.0f);
          float gg1 = fmaxf(fmaf(dd21, -invs2, 1.0f), 0.0f);
          plog[nb][2 * pp]     = gg0 * acc[nb][2 * pp];
          plog[nb][2 * pp + 1] = gg1 * acc[nb][2 * pp + 1];
        }
      }
    }

    // ---- online softmax (defer-rescale) ----
    float tm = fmaxf(fmaxf(plog[0][0], plog[0][1]), fmaxf(plog[0][2], plog[0][3]));
    #pragma unroll
    for (int nb = 1; nb < 4; nb++) {
      float t2 = fmaxf(fmaxf(plog[nb][0], plog[nb][1]),
                       fmaxf(plog[nb][2], plog[nb][3]));
      tm = fmaxf(tm, t2);
    }
    tm = fmaxf(tm, __shfl_xor(tm, 16));
    tm = fmaxf(tm, __shfl_xor(tm, 32));
    if (__any(tm > m + 11.0f)) {
      float nm = fmaxf(m, tm);
      float rsc = fexp2(m - nm);
      l *= rsc;
      #pragma unroll
      for (int n = 0; n < 8; n++) oacc[n] *= rsc;
      m = nm;
    }
    float psum = 0.0f;
    #pragma unroll
    for (int nb = 0; nb < 4; nb++)
      #pragma unroll
      for (int r = 0; r < 4; r++) {
        float p = fexp2(plog[nb][r] - m);
        plog[nb][r] = p;
        psum += p;
      }
    psum += __shfl_xor(psum, 16);
    psum += __shfl_xor(psum, 32);
    l += psum;

    unsigned pk[4][2];
    #pragma unroll
    for (int nb = 0; nb < 4; nb++) {
      pk[nb][0] = cvtpk(plog[nb][0], plog[nb][1]);
      pk[nb][1] = cvtpk(plog[nb][2], plog[nb][3]);
    }

    __syncthreads();   // ===== barrier B: Ks/cs2 reads done =====

    if (tt + 1 < ntiles) {   // commit K(t+1) -> Ks, coords -> cs2
      *(short8*)((char*)&Ks[0][0] + kofs) = kreg0;
      *(short8*)((char*)&Ks[0][0] + kofs + 32 * 256) = kreg1;
      if constexpr (GEO == 0) {
        if (tid < 64) {
          #pragma unroll
          for (int d = 0; d < 6; d++) cs2[d][tid] = cr[d];
        }
      }
    }

    // ---- O^T += V'(pre-permuted) @ P^T ----
    union U16 { i32x4 i; short8 s; };
    __builtin_amdgcn_s_setprio(1);
    #pragma unroll
    for (int ks2 = 0; ks2 < 2; ks2++) {
      U16 bfr;
      bfr.i[0] = (int)pk[2 * ks2][0];
      bfr.i[1] = (int)pk[2 * ks2][1];
      bfr.i[2] = (int)pk[2 * ks2 + 1][0];
      bfr.i[3] = (int)pk[2 * ks2 + 1][1];
      #pragma unroll
      for (int nb2 = 0; nb2 < 8; nb2++) {
        const char* vsrc = (const char*)&Vs[0][0] + (16 * nb2 + l15) * 128 +
                           (((4 * ks2 + g) ^ (l15 & 7)) << 4);
        short8 vf = *(const short8*)vsrc;
        oacc[nb2] = __builtin_amdgcn_mfma_f32_16x16x32_bf16(vf, bfr.s, oacc[nb2], 0, 0, 0);
      }
    }
    __builtin_amdgcn_s_setprio(0);

    __syncthreads();   // ===== barrier C: Vs reads done =====

    if (tt + 1 < ntiles) {   // commit V(t+1) -> Vs
      *(short8*)((char*)&Vs[0][0] + vofs) = vreg0;
      *(short8*)((char*)&Vs[0][0] + vofs + 64 * 128) = vreg1;
      if constexpr (GEO == 1) {
        #pragma unroll
        for (int nb = 0; nb < 4; nb++) gcur[nb] = gnxt[nb];
      }
    }
  }

  {
    float* op = Opart + ((size_t)seg * NPTS + qrow) * CH;
    #pragma unroll
    for (int nb2 = 0; nb2 < 8; nb2++)
      *(f32x4*)(op + 16 * nb2 + 4 * g) = oacc[nb2];
    if (g == 0) {
      ML[((size_t)seg * NPTS + qrow) * 2]     = m;
      ML[((size_t)seg * NPTS + qrow) * 2 + 1] = l;
    }
  }
}

// ---------------------------------------------------------------------------
// Kernel 4: fused combine(NS partials) + out-proj + residual + LN, 4 rows/blk.
// ---------------------------------------------------------------------------
__global__ __launch_bounds__(128) void k_out(
    const float* __restrict__ Opart, const float* __restrict__ ML, int NS,
    const float* __restrict__ W, const float* __restrict__ b,
    const float* __restrict__ g, const float* __restrict__ beta,
    const float* __restrict__ res, float* __restrict__ out) {
  const int j = threadIdx.x;
  const int r0 = blockIdx.x * 4;
  __shared__ float xs[4][CH];
  __shared__ float red[2][4];

  #pragma unroll
  for (int r = 0; r < 4; r++) {
    const int row = r0 + r;
    float M = -1e30f;
    for (int s = 0; s < NS; s++)
      M = fmaxf(M, ML[((size_t)s * NPTS + row) * 2]);
    float L = 0.0f, a = 0.0f;
    for (int s = 0; s < NS; s++) {
      float ms = ML[((size_t)s * NPTS + row) * 2];
      float ls = ML[((size_t)s * NPTS + row) * 2 + 1];
      float wsc = fexp2(ms - M);
      L += wsc * ls;
      a = fmaf(wsc, Opart[((size_t)s * NPTS + row) * CH + j], a);
    }
    xs[r][j] = a / L;
  }
  __syncthreads();

  float acc[4];
  const float bj = b[j];
  #pragma unroll
  for (int r = 0; r < 4; r++) acc[r] = bj;
  for (int kk = 0; kk < CH; kk++) {
    float wv_ = W[kk * CH + j];
    #pragma unroll
    for (int r = 0; r < 4; r++) acc[r] = fmaf(xs[r][kk], wv_, acc[r]);
  }
  #pragma unroll
  for (int r = 0; r < 4; r++) acc[r] += res[(r0 + r) * CH + j];

  const int wv2 = j >> 6, ln = j & 63;
  float sum[4];
  #pragma unroll
  for (int r = 0; r < 4; r++) sum[r] = acc[r];
  #pragma unroll
  for (int o = 32; o; o >>= 1) {
    #pragma unroll
    for (int r = 0; r < 4; r++) sum[r] += __shfl_xor(sum[r], o);
  }
  if (ln == 0) {
    #pragma unroll
    for (int r = 0; r < 4; r++) red[wv2][r] = sum[r];
  }
  __syncthreads();
  float dv[4];
  #pragma unroll
  for (int r = 0; r < 4; r++) {
    float mean = (red[0][r] + red[1][r]) * (1.0f / 128.0f);
    dv[r] = acc[r] - mean;
    sum[r] = dv[r] * dv[r];
  }
  #pragma unroll
  for (int o = 32; o; o >>= 1) {
    #pragma unroll
    for (int r = 0; r < 4; r++) sum[r] += __shfl_xor(sum[r], o);
  }
  __syncthreads();
  if (ln == 0) {
    #pragma unroll
    for (int r = 0; r < 4; r++) red[wv2][r] = sum[r];
  }
  __syncthreads();
  const float gj = g[j], betaj = beta[j];
  #pragma unroll
  for (int r = 0; r < 4; r++) {
    float var = (red[0][r] + red[1][r]) * (1.0f / 128.0f);
    out[(r0 + r) * CH + j] = dv[r] * rsqrtf(var + 1e-5f) * gj + betaj;
  }
}

// ---------------------------------------------------------------------------
// Kernel 5: final row normalize + classifier MLP + sigmoid
// ---------------------------------------------------------------------------
__global__ __launch_bounds__(128) void k_final(
    const float* __restrict__ F,
    const float* __restrict__ c1W, const float* __restrict__ c1b,
    const float* __restrict__ c2W, const float* __restrict__ c2b,
    const float* __restrict__ c3W, const float* __restrict__ c3b,
    float* __restrict__ out) {
  const int row = blockIdx.x, j = threadIdx.x;
  __shared__ float xs[CH];
  __shared__ float h1[32];
  __shared__ float h2[32];
  __shared__ float red[2];
  float x = F[row * CH + j];
  float ss = x * x;
  #pragma unroll
  for (int o = 32; o; o >>= 1) ss += __shfl_xor(ss, o);
  if ((j & 63) == 0) red[j >> 6] = ss;
  __syncthreads();
  float norm = sqrtf(red[0] + red[1]);
  float xn = x / fmaxf(norm, 1e-12f);
  xs[j] = xn;
  out[row * CH + j] = xn;
  __syncthreads();
  if (j < 32) {
    float a = c1b[j];
    for (int kk = 0; kk < CH; kk++) a = fmaf(xs[kk], c1W[kk * 32 + j], a);
    h1[j] = fmaxf(a, 0.0f);
  }
  __syncthreads();
  if (j < 32) {
    float a = c2b[j];
    #pragma unroll
    for (int kk = 0; kk < 32; kk++) a = fmaf(h1[kk], c2W[kk * 32 + j], a);
    h2[j] = fmaxf(a, 0.0f);
  }
  __syncthreads();
  if (j == 0) {
    float a = c3b[0];
    #pragma unroll
    for (int kk = 0; kk < 32; kk++) a = fmaf(h2[kk], c3W[kk], a);
    out[NPTS * CH + row] = 1.0f / (1.0f + __expf(-a));
  }
}

// ---------------------------------------------------------------------------
extern "C" void kernel_launch(void* const* d_in, const int* in_sizes, int n_in,
                              void* d_out, int out_size, void* d_ws, size_t ws_size,
                              hipStream_t stream) {
  const float* refp = (const float*)d_in[0];
  const float* srcp = (const float*)d_in[1];
  const float* cf   = (const float*)d_in[2];
  const float* Win  = (const float*)d_in[3];
  const float* bin  = (const float*)d_in[4];
  const float* mlpW = (const float*)d_in[5];
  const float* mlpb = (const float*)d_in[6];
  const float* mlpg = (const float*)d_in[7];
  const float* mlpbeta = (const float*)d_in[8];
  const float* Wq = (const float*)d_in[9];
  const float* bq = (const float*)d_in[10];
  const float* Wk = (const float*)d_in[11];
  const float* bk = (const float*)d_in[12];
  const float* Wv = (const float*)d_in[13];
  const float* bv = (const float*)d_in[14];
  const float* Wo = (const float*)d_in[15];
  const float* bo = (const float*)d_in[16];
  const float* lng = (const float*)d_in[17];
  const float* lnb = (const float*)d_in[18];
  const float* c1W = (const float*)d_in[19];
  const float* c1b = (const float*)d_in[20];
  const float* c2W = (const float*)d_in[21];
  const float* c2b = (const float*)d_in[22];
  const float* c3W = (const float*)d_in[23];
  const float* c3b = (const float*)d_in[24];
  float* out = (float*)d_out;

  const size_t NC = (size_t)NPTS * CH;
  const size_t geo_bytes = (size_t)NPTS * NPTS * 2;
  const size_t seg_bytes = NC * 4 + (size_t)NPTS * 8;
  const size_t base = 2 * NC * 4 + 3 * NC * 2;

  int NS = 0;
  bool useGeo = false;
  {
    const int c1_[4] = {24, 16, 12, 8};
    for (int i = 0; i < 4; i++)
      if (base + geo_bytes + (size_t)c1_[i] * seg_bytes <= ws_size) {
        NS = c1_[i]; useGeo = true; break;
      }
    if (!NS) {
      const int c2_[7] = {24, 16, 12, 8, 4, 2, 1};
      for (int i = 0; i < 7; i++)
        if (base + (size_t)c2_[i] * seg_bytes <= ws_size) { NS = c2_[i]; break; }
      if (!NS) NS = 1;
    }
  }

  char* p = (char*)d_ws;
  float* F = (float*)p;        p += NC * 4;
  float* T = (float*)p;        p += NC * 4;
  ushort* Qb = (ushort*)p;     p += NC * 2;
  ushort* Kb = (ushort*)p;     p += NC * 2;
  ushort* Vtb = (ushort*)p;    p += NC * 2;
  ushort* geo = nullptr;
  if (useGeo) { geo = (ushort*)p; p += geo_bytes; }
  float* Opart = (float*)p;    p += (size_t)NS * NC * 4;
  float* ML = (float*)p;
  const int ntiles = NPTS / 64 / NS;

  if (useGeo)
    k_geo<<<dim3(NPTS / 64, NPTS / 256), 256, 0, stream>>>(refp, srcp, geo);
  k_embed<<<NPTS, 128, 0, stream>>>(refp, srcp, cf, Win, bin, F);
  for (int i = 0; i < 3; i++) {
    const int o2 = i * CH * CH, o1 = i * CH;
    k_mlp_qkv<<<NPTS / 4, 128, 0, stream>>>(
        F, mlpW + o2, mlpb + o1, mlpg + o1, mlpbeta + o1,
        Wq + o2, bq + o1, Wk + o2, bk + o1, Wv + o2, bv + o1,
        T, Qb, Kb, Vtb);
    dim3 agrid(NPTS / 128, NS);
    if (useGeo)
      k_attn_mfma<1><<<agrid, 512, 0, stream>>>(Qb, Kb, Vtb, geo, refp, srcp,
                                                Opart, ML, ntiles);
    else
      k_attn_mfma<0><<<agrid, 512, 0, stream>>>(Qb, Kb, Vtb, nullptr, refp, srcp,
                                                Opart, ML, ntiles);
    k_out<<<NPTS / 4, 128, 0, stream>>>(Opart, ML, NS, Wo + o2, bo + o1,
                                        lng + o1, lnb + o1, T, F);
  }
  k_final<<<NPTS, 128, 0, stream>>>(F, c1W, c1b, c2W, c2b, c3W, c3b, out);
}

// Round 12
// 394.362 us; speedup vs baseline: 1.1216x; 1.1216x over previous
//
#include <hip/hip_runtime.h>
#include <math.h>

#define NPTS 6144
#define CH   128

typedef __attribute__((ext_vector_type(8))) short short8;
typedef __attribute__((ext_vector_type(4))) float f32x4;
typedef __attribute__((ext_vector_type(2))) float f32x2;
typedef __attribute__((ext_vector_type(4))) int   i32x4;

__device__ inline ushort f2bf(float f) {
  union { float f; unsigned u; } v; v.f = f;
  unsigned u = v.u;
  u += 0x7fff + ((u >> 16) & 1);   // round-to-nearest-even
  return (ushort)(u >> 16);
}

__device__ inline f32x2 splat2(float x) { return (f32x2){x, x}; }

__device__ inline float fsqrt(float x) {
  float r; asm("v_sqrt_f32 %0, %1" : "=v"(r) : "v"(x)); return r;
}
__device__ inline float fexp2(float x) {
  float r; asm("v_exp_f32 %0, %1" : "=v"(r) : "v"(x)); return r;
}
__device__ inline unsigned cvtpk(float a, float b) {
  unsigned r;
  asm("v_cvt_pk_bf16_f32 %0, %1, %2" : "=v"(r) : "v"(a), "v"(b));
  return r;
}

// ---------------------------------------------------------------------------
// Kernel 1: embedding  feat = [corr_feat, centered(kp)] @ W_in + b_in
// ---------------------------------------------------------------------------
__global__ __launch_bounds__(128) void k_embed(
    const float* __restrict__ refp, const float* __restrict__ srcp,
    const float* __restrict__ cf, const float* __restrict__ Win,
    const float* __restrict__ bin, float* __restrict__ out) {
  const int row = blockIdx.x, j = threadIdx.x;
  __shared__ float inb[12];
  __shared__ float mkp;
  if (j < 6)       inb[j] = cf[row * 6 + j];
  else if (j < 9)  inb[j] = refp[row * 3 + (j - 6)];
  else if (j < 12) inb[j] = srcp[row * 3 + (j - 9)];
  __syncthreads();
  if (j == 0) {
    float s = inb[6] + inb[7] + inb[8] + inb[9] + inb[10] + inb[11];
    mkp = s * (1.0f / 6.0f);
  }
  __syncthreads();
  float acc = bin[j];
  #pragma unroll
  for (int kk = 0; kk < 12; kk++) {
    float x = inb[kk] - (kk >= 6 ? mkp : 0.0f);
    acc = fmaf(x, Win[kk * CH + j], acc);
  }
  out[row * CH + j] = acc;
}

// ---------------------------------------------------------------------------
// Kernel 2: fused UnaryBlock (linear+LN+leaky) + QKV projection, 4 rows/block.
// V written transposed AND chunk-permuted (layout consumed by attn PV).
// ---------------------------------------------------------------------------
__global__ __launch_bounds__(128) void k_mlp_qkv(
    const float* __restrict__ X, const float* __restrict__ W,
    const float* __restrict__ b, const float* __restrict__ g,
    const float* __restrict__ beta,
    const float* __restrict__ Wq, const float* __restrict__ bq,
    const float* __restrict__ Wk, const float* __restrict__ bk,
    const float* __restrict__ Wv, const float* __restrict__ bv,
    float* __restrict__ T, ushort* __restrict__ Q, ushort* __restrict__ K,
    ushort* __restrict__ Vt) {
  const int j = threadIdx.x;
  const int r0 = blockIdx.x * 4;
  __shared__ float xs[4][CH];
  __shared__ float hs[4][CH];
  __shared__ float red[2][4];
  #pragma unroll
  for (int r = 0; r < 4; r++) xs[r][j] = X[(r0 + r) * CH + j];
  __syncthreads();

  float acc[4];
  const float bj = b[j];
  #pragma unroll
  for (int r = 0; r < 4; r++) acc[r] = bj;
  for (int kk = 0; kk < CH; kk++) {
    float wv_ = W[kk * CH + j];
    #pragma unroll
    for (int r = 0; r < 4; r++) acc[r] = fmaf(xs[r][kk], wv_, acc[r]);
  }
  const int wv2 = j >> 6, ln = j & 63;
  float sum[4];
  #pragma unroll
  for (int r = 0; r < 4; r++) sum[r] = acc[r];
  #pragma unroll
  for (int o = 32; o; o >>= 1) {
    #pragma unroll
    for (int r = 0; r < 4; r++) sum[r] += __shfl_xor(sum[r], o);
  }
  if (ln == 0) {
    #pragma unroll
    for (int r = 0; r < 4; r++) red[wv2][r] = sum[r];
  }
  __syncthreads();
  float dv[4];
  #pragma unroll
  for (int r = 0; r < 4; r++) {
    float mean = (red[0][r] + red[1][r]) * (1.0f / 128.0f);
    dv[r] = acc[r] - mean;
    sum[r] = dv[r] * dv[r];
  }
  #pragma unroll
  for (int o = 32; o; o >>= 1) {
    #pragma unroll
    for (int r = 0; r < 4; r++) sum[r] += __shfl_xor(sum[r], o);
  }
  __syncthreads();
  if (ln == 0) {
    #pragma unroll
    for (int r = 0; r < 4; r++) red[wv2][r] = sum[r];
  }
  __syncthreads();
  const float gj = g[j], betaj = beta[j];
  #pragma unroll
  for (int r = 0; r < 4; r++) {
    float var = (red[0][r] + red[1][r]) * (1.0f / 128.0f);
    float y = dv[r] * rsqrtf(var + 1e-5f) * gj + betaj;
    y = (y > 0.0f) ? y : 0.1f * y;
    T[(r0 + r) * CH + j] = y;
    hs[r][j] = y;
  }
  __syncthreads();

  float aq[4], ak[4], av[4];
  const float bqj = bq[j], bkj = bk[j], bvj = bv[j];
  #pragma unroll
  for (int r = 0; r < 4; r++) { aq[r] = bqj; ak[r] = bkj; av[r] = bvj; }
  for (int kk = 0; kk < CH; kk++) {
    float wq = Wq[kk * CH + j], wk = Wk[kk * CH + j], wv_ = Wv[kk * CH + j];
    #pragma unroll
    for (int r = 0; r < 4; r++) {
      float x = hs[r][kk];
      aq[r] = fmaf(x, wq, aq[r]);
      ak[r] = fmaf(x, wk, ak[r]);
      av[r] = fmaf(x, wv_, av[r]);
    }
  }
  const float scale = 0.12751879524143007f;  // 1/sqrt(128) * log2(e)
  #pragma unroll
  for (int r = 0; r < 4; r++) {
    Q[(r0 + r) * CH + j] = f2bf(aq[r] * scale);
    K[(r0 + r) * CH + j] = f2bf(ak[r]);
  }
  ushort4 vp;
  vp.x = f2bf(av[0]); vp.y = f2bf(av[1]); vp.z = f2bf(av[2]); vp.w = f2bf(av[3]);
  const int w0 = r0 & 63;
  const int pos = (r0 & ~63) + 32 * ((w0 >> 5) & 1) + 8 * ((w0 >> 2) & 3) +
                  4 * ((w0 >> 4) & 1);
  *(ushort4*)(Vt + (size_t)j * NPTS + pos) = vp;
}

// ---------------------------------------------------------------------------
// Kernel 3: MFMA flash attention, KV-split. 256 thr = 4 waves, 128 q/block;
// EACH WAVE OWNS 32 q-rows (two B-fragment sets) so every K/V A-frag
// ds_read_b128 feeds TWO MFMAs -> LDS traffic per output halved (the kernel
// was LDS-pipe-bound: 32KB LDS read /wave/tile vs ~640 MFMA cyc).
// Register-staged, single-buffered Ks/Vs, XOR-swizzled, 2 barriers/tile.
// 33.5 KB LDS, (256,2) -> 2 blocks/CU, no spill (~210 VGPR live).
// ---------------------------------------------------------------------------
__global__ __launch_bounds__(256, 2) void k_attn_mfma(
    const ushort* __restrict__ Q, const ushort* __restrict__ K,
    const ushort* __restrict__ Vt,
    const float* __restrict__ refp, const float* __restrict__ srcp,
    float* __restrict__ Opart, float* __restrict__ ML, int ntiles) {
  const int tid = threadIdx.x;
  const int w = tid >> 6, ln = tid & 63;
  const int l15 = ln & 15, g = ln >> 4;
  const int row0 = blockIdx.x * 128;
  const int seg = blockIdx.y;
  const int t0 = seg * ntiles;

  __shared__ ushort Ks[64][128];   // chunk c of key row r stored at c^(r&7)
  __shared__ ushort Vs[128][64];   // chunk c of ch row stored at c^(ch&7)
  __shared__ float cs2[6][64];

  // staging geometry: 256 thr x 4 chunks each for K (64x16) and V (128x8)
  int kofs[4], vofs[4];
  size_t kgo[4], vgo[4];
  #pragma unroll
  for (int s = 0; s < 4; s++) {
    int idx = tid + 256 * s;
    int kr = idx >> 4, kc = idx & 15;
    kofs[s] = kr * 256 + (((kc ^ (kr & 7)) << 4));
    kgo[s] = (size_t)kr * CH + kc * 8;
    int vr = idx >> 3, vc = idx & 7;
    vofs[s] = vr * 128 + (((vc ^ (vr & 7)) << 4));
    vgo[s] = (size_t)vr * NPTS + vc * 8;
  }

  short8 kreg[4], vreg[4];
  float cr[6];

  auto issue = [&](int t) {
    #pragma unroll
    for (int s = 0; s < 4; s++) {
      kreg[s] = *(const short8*)(K + (size_t)(t * 64) * CH + kgo[s]);
      vreg[s] = *(const short8*)(Vt + vgo[s] + t * 64);
    }
    if (tid < 64) {
      int gj = t * 64 + tid;
      cr[0] = refp[gj * 3]; cr[1] = refp[gj * 3 + 1]; cr[2] = refp[gj * 3 + 2];
      cr[3] = srcp[gj * 3]; cr[4] = srcp[gj * 3 + 1]; cr[5] = srcp[gj * 3 + 2];
    }
  };

  // two q-rows-sets per wave: q1 = qbase+l15, q2 = qbase+16+l15
  const int qbase = row0 + 32 * w;
  const int q1 = qbase + l15, q2 = qbase + 16 + l15;
  short8 qfA[4], qfB[4];
  {
    const ushort* qpA = Q + (size_t)q1 * CH + 8 * g;
    const ushort* qpB = Q + (size_t)q2 * CH + 8 * g;
    #pragma unroll
    for (int ks = 0; ks < 4; ks++) {
      qfA[ks] = *(const short8*)(qpA + 32 * ks);
      qfB[ks] = *(const short8*)(qpB + 32 * ks);
    }
  }
  const float rq10 = refp[q1 * 3], rq11 = refp[q1 * 3 + 1], rq12 = refp[q1 * 3 + 2];
  const float sq10 = srcp[q1 * 3], sq11 = srcp[q1 * 3 + 1], sq12 = srcp[q1 * 3 + 2];
  const float rq20 = refp[q2 * 3], rq21 = refp[q2 * 3 + 1], rq22 = refp[q2 * 3 + 2];
  const float sq20 = srcp[q2 * 3], sq21 = srcp[q2 * 3 + 1], sq22 = srcp[q2 * 3 + 2];

  f32x4 oA[8], oB[8];
  #pragma unroll
  for (int n = 0; n < 8; n++) {
    oA[n] = (f32x4){0.f, 0.f, 0.f, 0.f};
    oB[n] = (f32x4){0.f, 0.f, 0.f, 0.f};
  }
  float m1 = -1e30f, l1 = 0.0f, m2 = -1e30f, l2 = 0.0f;
  const float invs2 = 1.0f / (0.3f * 0.3f);

  // ---- prologue: stage tile t0 ----
  issue(t0);
  #pragma unroll
  for (int s = 0; s < 4; s++) {
    *(short8*)((char*)&Ks[0][0] + kofs[s]) = kreg[s];
    *(short8*)((char*)&Vs[0][0] + vofs[s]) = vreg[s];
  }
  if (tid < 64) {
    #pragma unroll
    for (int d = 0; d < 6; d++) cs2[d][tid] = cr[d];
  }
  __syncthreads();

  for (int tt = 0; tt < ntiles; tt++) {
    if (tt + 1 < ntiles) issue(t0 + tt + 1);

    // ---- S^T = K @ Q^T for both q-sets (A-frag read ONCE) ----
    f32x4 accA[4], accB[4];
    #pragma unroll
    for (int nb = 0; nb < 4; nb++) {
      accA[nb] = (f32x4){0.f, 0.f, 0.f, 0.f};
      accB[nb] = (f32x4){0.f, 0.f, 0.f, 0.f};
    }
    __builtin_amdgcn_s_setprio(1);
    #pragma unroll
    for (int ks = 0; ks < 4; ks++) {
      #pragma unroll
      for (int nb = 0; nb < 4; nb++) {
        const char* src = (const char*)&Ks[0][0] + (16 * nb + l15) * 256 +
                          (((4 * ks + g) ^ (l15 & 7)) << 4);
        short8 af = *(const short8*)src;
        accA[nb] = __builtin_amdgcn_mfma_f32_16x16x32_bf16(af, qfA[ks], accA[nb], 0, 0, 0);
        accB[nb] = __builtin_amdgcn_mfma_f32_16x16x32_bf16(af, qfB[ks], accB[nb], 0, 0, 0);
      }
    }
    __builtin_amdgcn_s_setprio(0);

    // ---- geo * S (log2 domain), shared key coords ----
    float pA[4][4], pB[4][4];
    #pragma unroll
    for (int nb = 0; nb < 4; nb++) {
      const int kb = 16 * nb + 4 * g;
      #pragma unroll
      for (int pp = 0; pp < 2; pp++) {
        const int k2 = kb + 2 * pp;
        f32x2 cx = *(const f32x2*)&cs2[0][k2];
        f32x2 cy = *(const f32x2*)&cs2[1][k2];
        f32x2 cz = *(const f32x2*)&cs2[2][k2];
        f32x2 sx = *(const f32x2*)&cs2[3][k2];
        f32x2 sy = *(const f32x2*)&cs2[4][k2];
        f32x2 sz = *(const f32x2*)&cs2[5][k2];
        // q1
        {
          f32x2 dx = splat2(rq10) - cx, dy = splat2(rq11) - cy, dz = splat2(rq12) - cz;
          f32x2 d2r = dx * dx + dy * dy + dz * dz;
          dx = splat2(sq10) - sx; dy = splat2(sq11) - sy; dz = splat2(sq12) - sz;
          f32x2 d2s = dx * dx + dy * dy + dz * dz;
          f32x2 prod = d2r * d2s, sum2 = d2r + d2s;
          float s0 = fsqrt(prod[0]), s1 = fsqrt(prod[1]);
          float dd20 = fmaf(-2.0f, s0, sum2[0]);
          float dd21 = fmaf(-2.0f, s1, sum2[1]);
          float gg0 = fmaxf(fmaf(dd20, -invs2, 1.0f), 0.0f);
          float gg1 = fmaxf(fmaf(dd21, -invs2, 1.0f), 0.0f);
          pA[nb][2 * pp]     = gg0 * accA[nb][2 * pp];
          pA[nb][2 * pp + 1] = gg1 * accA[nb][2 * pp + 1];
        }
        // q2
        {
          f32x2 dx = splat2(rq20) - cx, dy = splat2(rq21) - cy, dz = splat2(rq22) - cz;
          f32x2 d2r = dx * dx + dy * dy + dz * dz;
          dx = splat2(sq20) - sx; dy = splat2(sq21) - sy; dz = splat2(sq22) - sz;
          f32x2 d2s = dx * dx + dy * dy + dz * dz;
          f32x2 prod = d2r * d2s, sum2 = d2r + d2s;
          float s0 = fsqrt(prod[0]), s1 = fsqrt(prod[1]);
          float dd20 = fmaf(-2.0f, s0, sum2[0]);
          float dd21 = fmaf(-2.0f, s1, sum2[1]);
          float gg0 = fmaxf(fmaf(dd20, -invs2, 1.0f), 0.0f);
          float gg1 = fmaxf(fmaf(dd21, -invs2, 1.0f), 0.0f);
          pB[nb][2 * pp]     = gg0 * accB[nb][2 * pp];
          pB[nb][2 * pp + 1] = gg1 * accB[nb][2 * pp + 1];
        }
      }
    }

    // ---- online softmax (dual, defer-rescale) ----
    float tm1 = pA[0][0], tm2 = pB[0][0];
    #pragma unroll
    for (int nb = 0; nb < 4; nb++)
      #pragma unroll
      for (int r = 0; r < 4; r++) {
        tm1 = fmaxf(tm1, pA[nb][r]);
        tm2 = fmaxf(tm2, pB[nb][r]);
      }
    tm1 = fmaxf(tm1, __shfl_xor(tm1, 16));
    tm1 = fmaxf(tm1, __shfl_xor(tm1, 32));
    tm2 = fmaxf(tm2, __shfl_xor(tm2, 16));
    tm2 = fmaxf(tm2, __shfl_xor(tm2, 32));
    if (__any((tm1 > m1 + 11.0f) || (tm2 > m2 + 11.0f))) {
      float nm1 = fmaxf(m1, tm1), nm2 = fmaxf(m2, tm2);
      float rs1 = fexp2(m1 - nm1), rs2 = fexp2(m2 - nm2);
      l1 *= rs1; l2 *= rs2;
      #pragma unroll
      for (int n = 0; n < 8; n++) { oA[n] *= rs1; oB[n] *= rs2; }
      m1 = nm1; m2 = nm2;
    }
    float ps1 = 0.0f, ps2 = 0.0f;
    #pragma unroll
    for (int nb = 0; nb < 4; nb++)
      #pragma unroll
      for (int r = 0; r < 4; r++) {
        float a = fexp2(pA[nb][r] - m1);
        float b2 = fexp2(pB[nb][r] - m2);
        pA[nb][r] = a; pB[nb][r] = b2;
        ps1 += a; ps2 += b2;
      }
    ps1 += __shfl_xor(ps1, 16); ps1 += __shfl_xor(ps1, 32);
    ps2 += __shfl_xor(ps2, 16); ps2 += __shfl_xor(ps2, 32);
    l1 += ps1; l2 += ps2;

    unsigned pkA[4][2], pkB[4][2];
    #pragma unroll
    for (int nb = 0; nb < 4; nb++) {
      pkA[nb][0] = cvtpk(pA[nb][0], pA[nb][1]);
      pkA[nb][1] = cvtpk(pA[nb][2], pA[nb][3]);
      pkB[nb][0] = cvtpk(pB[nb][0], pB[nb][1]);
      pkB[nb][1] = cvtpk(pB[nb][2], pB[nb][3]);
    }

    __syncthreads();   // ===== barrier B: Ks/cs2 reads done =====

    if (tt + 1 < ntiles) {   // commit K(t+1), coords
      #pragma unroll
      for (int s = 0; s < 4; s++)
        *(short8*)((char*)&Ks[0][0] + kofs[s]) = kreg[s];
      if (tid < 64) {
        #pragma unroll
        for (int d = 0; d < 6; d++) cs2[d][tid] = cr[d];
      }
    }

    // ---- O^T += V' @ P^T for both q-sets (V-frag read ONCE) ----
    union U16 { i32x4 i; short8 s; };
    __builtin_amdgcn_s_setprio(1);
    #pragma unroll
    for (int ks2 = 0; ks2 < 2; ks2++) {
      U16 bfA, bfB;
      bfA.i[0] = (int)pkA[2 * ks2][0];
      bfA.i[1] = (int)pkA[2 * ks2][1];
      bfA.i[2] = (int)pkA[2 * ks2 + 1][0];
      bfA.i[3] = (int)pkA[2 * ks2 + 1][1];
      bfB.i[0] = (int)pkB[2 * ks2][0];
      bfB.i[1] = (int)pkB[2 * ks2][1];
      bfB.i[2] = (int)pkB[2 * ks2 + 1][0];
      bfB.i[3] = (int)pkB[2 * ks2 + 1][1];
      #pragma unroll
      for (int nb2 = 0; nb2 < 8; nb2++) {
        const char* vsrc = (const char*)&Vs[0][0] + (16 * nb2 + l15) * 128 +
                           (((4 * ks2 + g) ^ (l15 & 7)) << 4);
        short8 vf = *(const short8*)vsrc;
        oA[nb2] = __builtin_amdgcn_mfma_f32_16x16x32_bf16(vf, bfA.s, oA[nb2], 0, 0, 0);
        oB[nb2] = __builtin_amdgcn_mfma_f32_16x16x32_bf16(vf, bfB.s, oB[nb2], 0, 0, 0);
      }
    }
    __builtin_amdgcn_s_setprio(0);

    __syncthreads();   // ===== barrier C: Vs reads done =====

    if (tt + 1 < ntiles) {   // commit V(t+1)
      #pragma unroll
      for (int s = 0; s < 4; s++)
        *(short8*)((char*)&Vs[0][0] + vofs[s]) = vreg[s];
    }
  }

  {
    float* op1 = Opart + ((size_t)seg * NPTS + q1) * CH;
    float* op2 = Opart + ((size_t)seg * NPTS + q2) * CH;
    #pragma unroll
    for (int nb2 = 0; nb2 < 8; nb2++) {
      *(f32x4*)(op1 + 16 * nb2 + 4 * g) = oA[nb2];
      *(f32x4*)(op2 + 16 * nb2 + 4 * g) = oB[nb2];
    }
    if (g == 0) {
      ML[((size_t)seg * NPTS + q1) * 2]     = m1;
      ML[((size_t)seg * NPTS + q1) * 2 + 1] = l1;
      ML[((size_t)seg * NPTS + q2) * 2]     = m2;
      ML[((size_t)seg * NPTS + q2) * 2 + 1] = l2;
    }
  }
}

// ---------------------------------------------------------------------------
// Kernel 4: fused combine(NS partials) + out-proj + residual + LN, 4 rows/blk.
// ---------------------------------------------------------------------------
__global__ __launch_bounds__(128) void k_out(
    const float* __restrict__ Opart, const float* __restrict__ ML, int NS,
    const float* __restrict__ W, const float* __restrict__ b,
    const float* __restrict__ g, const float* __restrict__ beta,
    const float* __restrict__ res, float* __restrict__ out) {
  const int j = threadIdx.x;
  const int r0 = blockIdx.x * 4;
  __shared__ float xs[4][CH];
  __shared__ float red[2][4];

  #pragma unroll
  for (int r = 0; r < 4; r++) {
    const int row = r0 + r;
    float M = -1e30f;
    for (int s = 0; s < NS; s++)
      M = fmaxf(M, ML[((size_t)s * NPTS + row) * 2]);
    float L = 0.0f, a = 0.0f;
    for (int s = 0; s < NS; s++) {
      float ms = ML[((size_t)s * NPTS + row) * 2];
      float ls = ML[((size_t)s * NPTS + row) * 2 + 1];
      float wsc = fexp2(ms - M);
      L += wsc * ls;
      a = fmaf(wsc, Opart[((size_t)s * NPTS + row) * CH + j], a);
    }
    xs[r][j] = a / L;
  }
  __syncthreads();

  float acc[4];
  const float bj = b[j];
  #pragma unroll
  for (int r = 0; r < 4; r++) acc[r] = bj;
  for (int kk = 0; kk < CH; kk++) {
    float wv_ = W[kk * CH + j];
    #pragma unroll
    for (int r = 0; r < 4; r++) acc[r] = fmaf(xs[r][kk], wv_, acc[r]);
  }
  #pragma unroll
  for (int r = 0; r < 4; r++) acc[r] += res[(r0 + r) * CH + j];

  const int wv2 = j >> 6, ln = j & 63;
  float sum[4];
  #pragma unroll
  for (int r = 0; r < 4; r++) sum[r] = acc[r];
  #pragma unroll
  for (int o = 32; o; o >>= 1) {
    #pragma unroll
    for (int r = 0; r < 4; r++) sum[r] += __shfl_xor(sum[r], o);
  }
  if (ln == 0) {
    #pragma unroll
    for (int r = 0; r < 4; r++) red[wv2][r] = sum[r];
  }
  __syncthreads();
  float dv[4];
  #pragma unroll
  for (int r = 0; r < 4; r++) {
    float mean = (red[0][r] + red[1][r]) * (1.0f / 128.0f);
    dv[r] = acc[r] - mean;
    sum[r] = dv[r] * dv[r];
  }
  #pragma unroll
  for (int o = 32; o; o >>= 1) {
    #pragma unroll
    for (int r = 0; r < 4; r++) sum[r] += __shfl_xor(sum[r], o);
  }
  __syncthreads();
  if (ln == 0) {
    #pragma unroll
    for (int r = 0; r < 4; r++) red[wv2][r] = sum[r];
  }
  __syncthreads();
  const float gj = g[j], betaj = beta[j];
  #pragma unroll
  for (int r = 0; r < 4; r++) {
    float var = (red[0][r] + red[1][r]) * (1.0f / 128.0f);
    out[(r0 + r) * CH + j] = dv[r] * rsqrtf(var + 1e-5f) * gj + betaj;
  }
}

// ---------------------------------------------------------------------------
// Kernel 5: final row normalize + classifier MLP + sigmoid
// ---------------------------------------------------------------------------
__global__ __launch_bounds__(128) void k_final(
    const float* __restrict__ F,
    const float* __restrict__ c1W, const float* __restrict__ c1b,
    const float* __restrict__ c2W, const float* __restrict__ c2b,
    const float* __restrict__ c3W, const float* __restrict__ c3b,
    float* __restrict__ out) {
  const int row = blockIdx.x, j = threadIdx.x;
  __shared__ float xs[CH];
  __shared__ float h1[32];
  __shared__ float h2[32];
  __shared__ float red[2];
  float x = F[row * CH + j];
  float ss = x * x;
  #pragma unroll
  for (int o = 32; o; o >>= 1) ss += __shfl_xor(ss, o);
  if ((j & 63) == 0) red[j >> 6] = ss;
  __syncthreads();
  float norm = sqrtf(red[0] + red[1]);
  float xn = x / fmaxf(norm, 1e-12f);
  xs[j] = xn;
  out[row * CH + j] = xn;
  __syncthreads();
  if (j < 32) {
    float a = c1b[j];
    for (int kk = 0; kk < CH; kk++) a = fmaf(xs[kk], c1W[kk * 32 + j], a);
    h1[j] = fmaxf(a, 0.0f);
  }
  __syncthreads();
  if (j < 32) {
    float a = c2b[j];
    #pragma unroll
    for (int kk = 0; kk < 32; kk++) a = fmaf(h1[kk], c2W[kk * 32 + j], a);
    h2[j] = fmaxf(a, 0.0f);
  }
  __syncthreads();
  if (j == 0) {
    float a = c3b[0];
    #pragma unroll
    for (int kk = 0; kk < 32; kk++) a = fmaf(h2[kk], c3W[kk], a);
    out[NPTS * CH + row] = 1.0f / (1.0f + __expf(-a));
  }
}

// ---------------------------------------------------------------------------
extern "C" void kernel_launch(void* const* d_in, const int* in_sizes, int n_in,
                              void* d_out, int out_size, void* d_ws, size_t ws_size,
                              hipStream_t stream) {
  const float* refp = (const float*)d_in[0];
  const float* srcp = (const float*)d_in[1];
  const float* cf   = (const float*)d_in[2];
  const float* Win  = (const float*)d_in[3];
  const float* bin  = (const float*)d_in[4];
  const float* mlpW = (const float*)d_in[5];
  const float* mlpb = (const float*)d_in[6];
  const float* mlpg = (const float*)d_in[7];
  const float* mlpbeta = (const float*)d_in[8];
  const float* Wq = (const float*)d_in[9];
  const float* bq = (const float*)d_in[10];
  const float* Wk = (const float*)d_in[11];
  const float* bk = (const float*)d_in[12];
  const float* Wv = (const float*)d_in[13];
  const float* bv = (const float*)d_in[14];
  const float* Wo = (const float*)d_in[15];
  const float* bo = (const float*)d_in[16];
  const float* lng = (const float*)d_in[17];
  const float* lnb = (const float*)d_in[18];
  const float* c1W = (const float*)d_in[19];
  const float* c1b = (const float*)d_in[20];
  const float* c2W = (const float*)d_in[21];
  const float* c2b = (const float*)d_in[22];
  const float* c3W = (const float*)d_in[23];
  const float* c3b = (const float*)d_in[24];
  float* out = (float*)d_out;

  const size_t NC = (size_t)NPTS * CH;
  const size_t seg_bytes = NC * 4 + (size_t)NPTS * 8;
  const size_t base = 2 * NC * 4 + 3 * NC * 2;

  int NS = 1;
  {
    const int cands[8] = {16, 12, 8, 6, 4, 3, 2, 1};
    for (int i = 0; i < 8; i++)
      if (base + (size_t)cands[i] * seg_bytes <= ws_size) { NS = cands[i]; break; }
  }

  char* p = (char*)d_ws;
  float* F = (float*)p;        p += NC * 4;
  float* T = (float*)p;        p += NC * 4;
  ushort* Qb = (ushort*)p;     p += NC * 2;
  ushort* Kb = (ushort*)p;     p += NC * 2;
  ushort* Vtb = (ushort*)p;    p += NC * 2;
  float* Opart = (float*)p;    p += (size_t)NS * NC * 4;
  float* ML = (float*)p;
  const int ntiles = NPTS / 64 / NS;

  k_embed<<<NPTS, 128, 0, stream>>>(refp, srcp, cf, Win, bin, F);
  for (int i = 0; i < 3; i++) {
    const int o2 = i * CH * CH, o1 = i * CH;
    k_mlp_qkv<<<NPTS / 4, 128, 0, stream>>>(
        F, mlpW + o2, mlpb + o1, mlpg + o1, mlpbeta + o1,
        Wq + o2, bq + o1, Wk + o2, bk + o1, Wv + o2, bv + o1,
        T, Qb, Kb, Vtb);
    dim3 agrid(NPTS / 128, NS);
    k_attn_mfma<<<agrid, 256, 0, stream>>>(Qb, Kb, Vtb, refp, srcp,
                                           Opart, ML, ntiles);
    k_out<<<NPTS / 4, 128, 0, stream>>>(Opart, ML, NS, Wo + o2, bo + o1,
                                        lng + o1, lnb + o1, T, F);
  }
  k_final<<<NPTS, 128, 0, stream>>>(F, c1W, c1b, c2W, c2b, c3W, c3b, out);
}

// Round 13
// 356.572 us; speedup vs baseline: 1.2405x; 1.1060x over previous
//
#include <hip/hip_runtime.h>
#include <math.h>

#define NPTS 6144
#define CH   128

typedef __attribute__((ext_vector_type(8))) short short8;
typedef __attribute__((ext_vector_type(4))) float f32x4;
typedef __attribute__((ext_vector_type(2))) float f32x2;
typedef __attribute__((ext_vector_type(4))) int   i32x4;
typedef __attribute__((ext_vector_type(2))) unsigned u32x2;

__device__ inline ushort f2bf(float f) {
  union { float f; unsigned u; } v; v.f = f;
  unsigned u = v.u;
  u += 0x7fff + ((u >> 16) & 1);   // round-to-nearest-even
  return (ushort)(u >> 16);
}
__device__ inline float bf2f(ushort h) {
  union { unsigned u; float f; } v; v.u = ((unsigned)h) << 16; return v.f;
}

__device__ inline f32x2 splat2(float x) { return (f32x2){x, x}; }

__device__ inline float fsqrt(float x) {
  float r; asm("v_sqrt_f32 %0, %1" : "=v"(r) : "v"(x)); return r;
}
__device__ inline float fexp2(float x) {
  float r; asm("v_exp_f32 %0, %1" : "=v"(r) : "v"(x)); return r;
}
__device__ inline unsigned cvtpk(float a, float b) {
  unsigned r;
  asm("v_cvt_pk_bf16_f32 %0, %1, %2" : "=v"(r) : "v"(a), "v"(b));
  return r;
}
__device__ inline float h2f(ushort h) {
  float r; asm("v_cvt_f32_f16 %0, %1" : "=v"(r) : "v"((unsigned)h)); return r;
}
__device__ inline ushort f2h(float f) {
  unsigned r; asm("v_cvt_f16_f32 %0, %1" : "=v"(r) : "v"(f)); return (ushort)r;
}

// ---------------------------------------------------------------------------
// Kernel 0 (optional): precompute geo fp16 [NPTS][NPTS].  Layer-invariant.
// COALESCED: wave w owns q-row blockIdx.x*4+w; lane ln writes key ln+64i
// (contiguous 128B per wave-store).  Key coords staged coord-major [6][256]
// (conflict-free: lanes read consecutive words).
// ---------------------------------------------------------------------------
__global__ __launch_bounds__(256) void k_geo(
    const float* __restrict__ refp, const float* __restrict__ srcp,
    ushort* __restrict__ geo) {
  const int tid = threadIdx.x;
  const int w = tid >> 6, ln = tid & 63;
  const int q = blockIdx.x * 4 + w;
  __shared__ float kco[6][256];
  const float rq0 = refp[q * 3], rq1 = refp[q * 3 + 1], rq2 = refp[q * 3 + 2];
  const float sq0 = srcp[q * 3], sq1 = srcp[q * 3 + 1], sq2 = srcp[q * 3 + 2];
  const float invs2 = 1.0f / (0.3f * 0.3f);
  for (int kb = 0; kb < NPTS / 256; kb++) {
    __syncthreads();
    {
      int k = kb * 256 + tid;
      kco[0][tid] = refp[k * 3]; kco[1][tid] = refp[k * 3 + 1];
      kco[2][tid] = refp[k * 3 + 2];
      kco[3][tid] = srcp[k * 3]; kco[4][tid] = srcp[k * 3 + 1];
      kco[5][tid] = srcp[k * 3 + 2];
    }
    __syncthreads();
    #pragma unroll
    for (int i = 0; i < 4; i++) {
      int kl = ln + 64 * i;
      float dx = rq0 - kco[0][kl], dy = rq1 - kco[1][kl], dz = rq2 - kco[2][kl];
      float d2r = dx * dx + dy * dy + dz * dz;
      dx = sq0 - kco[3][kl]; dy = sq1 - kco[4][kl]; dz = sq2 - kco[5][kl];
      float d2s = dx * dx + dy * dy + dz * dz;
      float dd2 = fmaf(-2.0f, fsqrt(d2r * d2s), d2r + d2s);
      float gg = fmaxf(fmaf(dd2, -invs2, 1.0f), 0.0f);
      geo[(size_t)q * NPTS + kb * 256 + kl] = f2h(gg);
    }
  }
}

// ---------------------------------------------------------------------------
// Kernel 1: embedding  feat = [corr_feat, centered(kp)] @ W_in + b_in
// ---------------------------------------------------------------------------
__global__ __launch_bounds__(128) void k_embed(
    const float* __restrict__ refp, const float* __restrict__ srcp,
    const float* __restrict__ cf, const float* __restrict__ Win,
    const float* __restrict__ bin, float* __restrict__ out) {
  const int row = blockIdx.x, j = threadIdx.x;
  __shared__ float inb[12];
  __shared__ float mkp;
  if (j < 6)       inb[j] = cf[row * 6 + j];
  else if (j < 9)  inb[j] = refp[row * 3 + (j - 6)];
  else if (j < 12) inb[j] = srcp[row * 3 + (j - 9)];
  __syncthreads();
  if (j == 0) {
    float s = inb[6] + inb[7] + inb[8] + inb[9] + inb[10] + inb[11];
    mkp = s * (1.0f / 6.0f);
  }
  __syncthreads();
  float acc = bin[j];
  #pragma unroll
  for (int kk = 0; kk < 12; kk++) {
    float x = inb[kk] - (kk >= 6 ? mkp : 0.0f);
    acc = fmaf(x, Win[kk * CH + j], acc);
  }
  out[row * CH + j] = acc;
}

// ---------------------------------------------------------------------------
// Kernel 2: fused UnaryBlock (linear+LN+leaky) + QKV projection, 4 rows/block.
// V written transposed AND chunk-permuted (layout consumed by attn PV).
// ---------------------------------------------------------------------------
__global__ __launch_bounds__(128) void k_mlp_qkv(
    const float* __restrict__ X, const float* __restrict__ W,
    const float* __restrict__ b, const float* __restrict__ g,
    const float* __restrict__ beta,
    const float* __restrict__ Wq, const float* __restrict__ bq,
    const float* __restrict__ Wk, const float* __restrict__ bk,
    const float* __restrict__ Wv, const float* __restrict__ bv,
    float* __restrict__ T, ushort* __restrict__ Q, ushort* __restrict__ K,
    ushort* __restrict__ Vt) {
  const int j = threadIdx.x;
  const int r0 = blockIdx.x * 4;
  __shared__ float xs[4][CH];
  __shared__ float hs[4][CH];
  __shared__ float red[2][4];
  #pragma unroll
  for (int r = 0; r < 4; r++) xs[r][j] = X[(r0 + r) * CH + j];
  __syncthreads();

  float acc[4];
  const float bj = b[j];
  #pragma unroll
  for (int r = 0; r < 4; r++) acc[r] = bj;
  for (int kk = 0; kk < CH; kk++) {
    float wv_ = W[kk * CH + j];
    #pragma unroll
    for (int r = 0; r < 4; r++) acc[r] = fmaf(xs[r][kk], wv_, acc[r]);
  }
  const int wv2 = j >> 6, ln = j & 63;
  float sum[4];
  #pragma unroll
  for (int r = 0; r < 4; r++) sum[r] = acc[r];
  #pragma unroll
  for (int o = 32; o; o >>= 1) {
    #pragma unroll
    for (int r = 0; r < 4; r++) sum[r] += __shfl_xor(sum[r], o);
  }
  if (ln == 0) {
    #pragma unroll
    for (int r = 0; r < 4; r++) red[wv2][r] = sum[r];
  }
  __syncthreads();
  float dv[4];
  #pragma unroll
  for (int r = 0; r < 4; r++) {
    float mean = (red[0][r] + red[1][r]) * (1.0f / 128.0f);
    dv[r] = acc[r] - mean;
    sum[r] = dv[r] * dv[r];
  }
  #pragma unroll
  for (int o = 32; o; o >>= 1) {
    #pragma unroll
    for (int r = 0; r < 4; r++) sum[r] += __shfl_xor(sum[r], o);
  }
  __syncthreads();
  if (ln == 0) {
    #pragma unroll
    for (int r = 0; r < 4; r++) red[wv2][r] = sum[r];
  }
  __syncthreads();
  const float gj = g[j], betaj = beta[j];
  #pragma unroll
  for (int r = 0; r < 4; r++) {
    float var = (red[0][r] + red[1][r]) * (1.0f / 128.0f);
    float y = dv[r] * rsqrtf(var + 1e-5f) * gj + betaj;
    y = (y > 0.0f) ? y : 0.1f * y;
    T[(r0 + r) * CH + j] = y;
    hs[r][j] = y;
  }
  __syncthreads();

  float aq[4], ak[4], av[4];
  const float bqj = bq[j], bkj = bk[j], bvj = bv[j];
  #pragma unroll
  for (int r = 0; r < 4; r++) { aq[r] = bqj; ak[r] = bkj; av[r] = bvj; }
  for (int kk = 0; kk < CH; kk++) {
    float wq = Wq[kk * CH + j], wk = Wk[kk * CH + j], wv_ = Wv[kk * CH + j];
    #pragma unroll
    for (int r = 0; r < 4; r++) {
      float x = hs[r][kk];
      aq[r] = fmaf(x, wq, aq[r]);
      ak[r] = fmaf(x, wk, ak[r]);
      av[r] = fmaf(x, wv_, av[r]);
    }
  }
  const float scale = 0.12751879524143007f;  // 1/sqrt(128) * log2(e)
  #pragma unroll
  for (int r = 0; r < 4; r++) {
    Q[(r0 + r) * CH + j] = f2bf(aq[r] * scale);
    K[(r0 + r) * CH + j] = f2bf(ak[r]);
  }
  ushort4 vp;
  vp.x = f2bf(av[0]); vp.y = f2bf(av[1]); vp.z = f2bf(av[2]); vp.w = f2bf(av[3]);
  const int w0 = r0 & 63;
  const int pos = (r0 & ~63) + 32 * ((w0 >> 5) & 1) + 8 * ((w0 >> 2) & 3) +
                  4 * ((w0 >> 4) & 1);
  *(ushort4*)(Vt + (size_t)j * NPTS + pos) = vp;
}

// ---------------------------------------------------------------------------
// Kernel 3: MFMA flash attention, KV-split, dual-q (each wave owns 32 q-rows,
// every K/V ds_read_b128 feeds two MFMAs).  Register-staged, single-buffered
// Ks/Vs, XOR-swizzled, 2 barriers/tile.  Opart written bf16.
// GEO=1: geo from precomputed fp16 table (loads issue under QK MFMA phase);
// GEO=0: inline geo from LDS-staged coords (fallback).
// ---------------------------------------------------------------------------
template <int GEO>
__global__ __launch_bounds__(256, 2) void k_attn_mfma(
    const ushort* __restrict__ Q, const ushort* __restrict__ K,
    const ushort* __restrict__ Vt, const ushort* __restrict__ geo,
    const float* __restrict__ refp, const float* __restrict__ srcp,
    ushort* __restrict__ Opart, float* __restrict__ ML, int ntiles) {
  const int tid = threadIdx.x;
  const int w = tid >> 6, ln = tid & 63;
  const int l15 = ln & 15, g = ln >> 4;
  const int row0 = blockIdx.x * 128;
  const int seg = blockIdx.y;
  const int t0 = seg * ntiles;

  __shared__ ushort Ks[64][128];   // chunk c of key row r stored at c^(r&7)
  __shared__ ushort Vs[128][64];   // chunk c of ch row stored at c^(ch&7)
  __shared__ float cs2[6][(GEO == 0) ? 64 : 4];

  int kofs[4], vofs[4];
  size_t kgo[4], vgo[4];
  #pragma unroll
  for (int s = 0; s < 4; s++) {
    int idx = tid + 256 * s;
    int kr = idx >> 4, kc = idx & 15;
    kofs[s] = kr * 256 + (((kc ^ (kr & 7)) << 4));
    kgo[s] = (size_t)kr * CH + kc * 8;
    int vr = idx >> 3, vc = idx & 7;
    vofs[s] = vr * 128 + (((vc ^ (vr & 7)) << 4));
    vgo[s] = (size_t)vr * NPTS + vc * 8;
  }

  short8 kreg[4], vreg[4];
  float cr[6];

  auto issue = [&](int t) {
    #pragma unroll
    for (int s = 0; s < 4; s++) {
      kreg[s] = *(const short8*)(K + (size_t)(t * 64) * CH + kgo[s]);
      vreg[s] = *(const short8*)(Vt + vgo[s] + t * 64);
    }
    if constexpr (GEO == 0) {
      if (tid < 64) {
        int gj = t * 64 + tid;
        cr[0] = refp[gj * 3]; cr[1] = refp[gj * 3 + 1]; cr[2] = refp[gj * 3 + 2];
        cr[3] = srcp[gj * 3]; cr[4] = srcp[gj * 3 + 1]; cr[5] = srcp[gj * 3 + 2];
      }
    }
  };

  const int qbase = row0 + 32 * w;
  const int q1 = qbase + l15, q2 = qbase + 16 + l15;
  short8 qfA[4], qfB[4];
  {
    const ushort* qpA = Q + (size_t)q1 * CH + 8 * g;
    const ushort* qpB = Q + (size_t)q2 * CH + 8 * g;
    #pragma unroll
    for (int ks = 0; ks < 4; ks++) {
      qfA[ks] = *(const short8*)(qpA + 32 * ks);
      qfB[ks] = *(const short8*)(qpB + 32 * ks);
    }
  }
  float rq10 = 0, rq11 = 0, rq12 = 0, sq10 = 0, sq11 = 0, sq12 = 0;
  float rq20 = 0, rq21 = 0, rq22 = 0, sq20 = 0, sq21 = 0, sq22 = 0;
  if constexpr (GEO == 0) {
    rq10 = refp[q1 * 3]; rq11 = refp[q1 * 3 + 1]; rq12 = refp[q1 * 3 + 2];
    sq10 = srcp[q1 * 3]; sq11 = srcp[q1 * 3 + 1]; sq12 = srcp[q1 * 3 + 2];
    rq20 = refp[q2 * 3]; rq21 = refp[q2 * 3 + 1]; rq22 = refp[q2 * 3 + 2];
    sq20 = srcp[q2 * 3]; sq21 = srcp[q2 * 3 + 1]; sq22 = srcp[q2 * 3 + 2];
  }

  f32x4 oA[8], oB[8];
  #pragma unroll
  for (int n = 0; n < 8; n++) {
    oA[n] = (f32x4){0.f, 0.f, 0.f, 0.f};
    oB[n] = (f32x4){0.f, 0.f, 0.f, 0.f};
  }
  float m1 = -1e30f, l1 = 0.0f, m2 = -1e30f, l2 = 0.0f;
  const float invs2 = 1.0f / (0.3f * 0.3f);

  issue(t0);
  #pragma unroll
  for (int s = 0; s < 4; s++) {
    *(short8*)((char*)&Ks[0][0] + kofs[s]) = kreg[s];
    *(short8*)((char*)&Vs[0][0] + vofs[s]) = vreg[s];
  }
  if constexpr (GEO == 0) {
    if (tid < 64) {
      #pragma unroll
      for (int d = 0; d < 6; d++) cs2[d][tid] = cr[d];
    }
  }
  __syncthreads();

  for (int tt = 0; tt < ntiles; tt++) {
    const int t = t0 + tt;
    if (tt + 1 < ntiles) issue(t + 1);

    ushort4 gA[4], gB[4];
    if constexpr (GEO == 1) {   // current-tile geo; latency hides under QK MFMA
      const ushort* gp1 = geo + (size_t)q1 * NPTS + t * 64 + 4 * g;
      const ushort* gp2 = geo + (size_t)q2 * NPTS + t * 64 + 4 * g;
      #pragma unroll
      for (int nb = 0; nb < 4; nb++) {
        gA[nb] = *(const ushort4*)(gp1 + 16 * nb);
        gB[nb] = *(const ushort4*)(gp2 + 16 * nb);
      }
    }

    // ---- S^T = K @ Q^T for both q-sets (A-frag read ONCE) ----
    f32x4 accA[4], accB[4];
    #pragma unroll
    for (int nb = 0; nb < 4; nb++) {
      accA[nb] = (f32x4){0.f, 0.f, 0.f, 0.f};
      accB[nb] = (f32x4){0.f, 0.f, 0.f, 0.f};
    }
    __builtin_amdgcn_s_setprio(1);
    #pragma unroll
    for (int ks = 0; ks < 4; ks++) {
      #pragma unroll
      for (int nb = 0; nb < 4; nb++) {
        const char* src = (const char*)&Ks[0][0] + (16 * nb + l15) * 256 +
                          (((4 * ks + g) ^ (l15 & 7)) << 4);
        short8 af = *(const short8*)src;
        accA[nb] = __builtin_amdgcn_mfma_f32_16x16x32_bf16(af, qfA[ks], accA[nb], 0, 0, 0);
        accB[nb] = __builtin_amdgcn_mfma_f32_16x16x32_bf16(af, qfB[ks], accB[nb], 0, 0, 0);
      }
    }
    __builtin_amdgcn_s_setprio(0);

    // ---- geo * S (log2 domain) ----
    float pA[4][4], pB[4][4];
    if constexpr (GEO == 1) {
      #pragma unroll
      for (int nb = 0; nb < 4; nb++) {
        pA[nb][0] = h2f(gA[nb].x) * accA[nb][0];
        pA[nb][1] = h2f(gA[nb].y) * accA[nb][1];
        pA[nb][2] = h2f(gA[nb].z) * accA[nb][2];
        pA[nb][3] = h2f(gA[nb].w) * accA[nb][3];
        pB[nb][0] = h2f(gB[nb].x) * accB[nb][0];
        pB[nb][1] = h2f(gB[nb].y) * accB[nb][1];
        pB[nb][2] = h2f(gB[nb].z) * accB[nb][2];
        pB[nb][3] = h2f(gB[nb].w) * accB[nb][3];
      }
    } else {
      #pragma unroll
      for (int nb = 0; nb < 4; nb++) {
        const int kb = 16 * nb + 4 * g;
        #pragma unroll
        for (int pp = 0; pp < 2; pp++) {
          const int k2 = kb + 2 * pp;
          f32x2 cx = *(const f32x2*)&cs2[0][k2];
          f32x2 cy = *(const f32x2*)&cs2[1][k2];
          f32x2 cz = *(const f32x2*)&cs2[2][k2];
          f32x2 sx = *(const f32x2*)&cs2[3][k2];
          f32x2 sy = *(const f32x2*)&cs2[4][k2];
          f32x2 sz = *(const f32x2*)&cs2[5][k2];
          {
            f32x2 dx = splat2(rq10) - cx, dy = splat2(rq11) - cy, dz = splat2(rq12) - cz;
            f32x2 d2r = dx * dx + dy * dy + dz * dz;
            dx = splat2(sq10) - sx; dy = splat2(sq11) - sy; dz = splat2(sq12) - sz;
            f32x2 d2s = dx * dx + dy * dy + dz * dz;
            f32x2 prod = d2r * d2s, sum2 = d2r + d2s;
            float s0 = fsqrt(prod[0]), s1 = fsqrt(prod[1]);
            float dd20 = fmaf(-2.0f, s0, sum2[0]);
            float dd21 = fmaf(-2.0f, s1, sum2[1]);
            float gg0 = fmaxf(fmaf(dd20, -invs2, 1.0f), 0.0f);
            float gg1 = fmaxf(fmaf(dd21, -invs2, 1.0f), 0.0f);
            pA[nb][2 * pp]     = gg0 * accA[nb][2 * pp];
            pA[nb][2 * pp + 1] = gg1 * accA[nb][2 * pp + 1];
          }
          {
            f32x2 dx = splat2(rq20) - cx, dy = splat2(rq21) - cy, dz = splat2(rq22) - cz;
            f32x2 d2r = dx * dx + dy * dy + dz * dz;
            dx = splat2(sq20) - sx; dy = splat2(sq21) - sy; dz = splat2(sq22) - sz;
            f32x2 d2s = dx * dx + dy * dy + dz * dz;
            f32x2 prod = d2r * d2s, sum2 = d2r + d2s;
            float s0 = fsqrt(prod[0]), s1 = fsqrt(prod[1]);
            float dd20 = fmaf(-2.0f, s0, sum2[0]);
            float dd21 = fmaf(-2.0f, s1, sum2[1]);
            float gg0 = fmaxf(fmaf(dd20, -invs2, 1.0f), 0.0f);
            float gg1 = fmaxf(fmaf(dd21, -invs2, 1.0f), 0.0f);
            pB[nb][2 * pp]     = gg0 * accB[nb][2 * pp];
            pB[nb][2 * pp + 1] = gg1 * accB[nb][2 * pp + 1];
          }
        }
      }
    }

    // ---- online softmax (dual, defer-rescale) ----
    float tm1 = pA[0][0], tm2 = pB[0][0];
    #pragma unroll
    for (int nb = 0; nb < 4; nb++)
      #pragma unroll
      for (int r = 0; r < 4; r++) {
        tm1 = fmaxf(tm1, pA[nb][r]);
        tm2 = fmaxf(tm2, pB[nb][r]);
      }
    tm1 = fmaxf(tm1, __shfl_xor(tm1, 16));
    tm1 = fmaxf(tm1, __shfl_xor(tm1, 32));
    tm2 = fmaxf(tm2, __shfl_xor(tm2, 16));
    tm2 = fmaxf(tm2, __shfl_xor(tm2, 32));
    if (__any((tm1 > m1 + 11.0f) || (tm2 > m2 + 11.0f))) {
      float nm1 = fmaxf(m1, tm1), nm2 = fmaxf(m2, tm2);
      float rs1 = fexp2(m1 - nm1), rs2 = fexp2(m2 - nm2);
      l1 *= rs1; l2 *= rs2;
      #pragma unroll
      for (int n = 0; n < 8; n++) { oA[n] *= rs1; oB[n] *= rs2; }
      m1 = nm1; m2 = nm2;
    }
    float ps1 = 0.0f, ps2 = 0.0f;
    #pragma unroll
    for (int nb = 0; nb < 4; nb++)
      #pragma unroll
      for (int r = 0; r < 4; r++) {
        float a = fexp2(pA[nb][r] - m1);
        float b2 = fexp2(pB[nb][r] - m2);
        pA[nb][r] = a; pB[nb][r] = b2;
        ps1 += a; ps2 += b2;
      }
    ps1 += __shfl_xor(ps1, 16); ps1 += __shfl_xor(ps1, 32);
    ps2 += __shfl_xor(ps2, 16); ps2 += __shfl_xor(ps2, 32);
    l1 += ps1; l2 += ps2;

    unsigned pkA[4][2], pkB[4][2];
    #pragma unroll
    for (int nb = 0; nb < 4; nb++) {
      pkA[nb][0] = cvtpk(pA[nb][0], pA[nb][1]);
      pkA[nb][1] = cvtpk(pA[nb][2], pA[nb][3]);
      pkB[nb][0] = cvtpk(pB[nb][0], pB[nb][1]);
      pkB[nb][1] = cvtpk(pB[nb][2], pB[nb][3]);
    }

    __syncthreads();   // ===== barrier B: Ks/cs2 reads done =====

    if (tt + 1 < ntiles) {
      #pragma unroll
      for (int s = 0; s < 4; s++)
        *(short8*)((char*)&Ks[0][0] + kofs[s]) = kreg[s];
      if constexpr (GEO == 0) {
        if (tid < 64) {
          #pragma unroll
          for (int d = 0; d < 6; d++) cs2[d][tid] = cr[d];
        }
      }
    }

    // ---- O^T += V' @ P^T for both q-sets (V-frag read ONCE) ----
    union U16 { i32x4 i; short8 s; };
    __builtin_amdgcn_s_setprio(1);
    #pragma unroll
    for (int ks2 = 0; ks2 < 2; ks2++) {
      U16 bfA, bfB;
      bfA.i[0] = (int)pkA[2 * ks2][0];
      bfA.i[1] = (int)pkA[2 * ks2][1];
      bfA.i[2] = (int)pkA[2 * ks2 + 1][0];
      bfA.i[3] = (int)pkA[2 * ks2 + 1][1];
      bfB.i[0] = (int)pkB[2 * ks2][0];
      bfB.i[1] = (int)pkB[2 * ks2][1];
      bfB.i[2] = (int)pkB[2 * ks2 + 1][0];
      bfB.i[3] = (int)pkB[2 * ks2 + 1][1];
      #pragma unroll
      for (int nb2 = 0; nb2 < 8; nb2++) {
        const char* vsrc = (const char*)&Vs[0][0] + (16 * nb2 + l15) * 128 +
                           (((4 * ks2 + g) ^ (l15 & 7)) << 4);
        short8 vf = *(const short8*)vsrc;
        oA[nb2] = __builtin_amdgcn_mfma_f32_16x16x32_bf16(vf, bfA.s, oA[nb2], 0, 0, 0);
        oB[nb2] = __builtin_amdgcn_mfma_f32_16x16x32_bf16(vf, bfB.s, oB[nb2], 0, 0, 0);
      }
    }
    __builtin_amdgcn_s_setprio(0);

    __syncthreads();   // ===== barrier C: Vs reads done =====

    if (tt + 1 < ntiles) {
      #pragma unroll
      for (int s = 0; s < 4; s++)
        *(short8*)((char*)&Vs[0][0] + vofs[s]) = vreg[s];
    }
  }

  {
    ushort* op1 = Opart + ((size_t)seg * NPTS + q1) * CH;
    ushort* op2 = Opart + ((size_t)seg * NPTS + q2) * CH;
    #pragma unroll
    for (int nb2 = 0; nb2 < 8; nb2++) {
      u32x2 a, b2;
      a[0] = cvtpk(oA[nb2][0], oA[nb2][1]);
      a[1] = cvtpk(oA[nb2][2], oA[nb2][3]);
      b2[0] = cvtpk(oB[nb2][0], oB[nb2][1]);
      b2[1] = cvtpk(oB[nb2][2], oB[nb2][3]);
      *(u32x2*)(op1 + 16 * nb2 + 4 * g) = a;
      *(u32x2*)(op2 + 16 * nb2 + 4 * g) = b2;
    }
    if (g == 0) {
      ML[((size_t)seg * NPTS + q1) * 2]     = m1;
      ML[((size_t)seg * NPTS + q1) * 2 + 1] = l1;
      ML[((size_t)seg * NPTS + q2) * 2]     = m2;
      ML[((size_t)seg * NPTS + q2) * 2 + 1] = l2;
    }
  }
}

// ---------------------------------------------------------------------------
// Kernel 4: fused combine(NS bf16 partials) + out-proj + residual + LN.
// ---------------------------------------------------------------------------
__global__ __launch_bounds__(128) void k_out(
    const ushort* __restrict__ Opart, const float* __restrict__ ML, int NS,
    const float* __restrict__ W, const float* __restrict__ b,
    const float* __restrict__ g, const float* __restrict__ beta,
    const float* __restrict__ res, float* __restrict__ out) {
  const int j = threadIdx.x;
  const int r0 = blockIdx.x * 4;
  __shared__ float xs[4][CH];
  __shared__ float red[2][4];

  #pragma unroll
  for (int r = 0; r < 4; r++) {
    const int row = r0 + r;
    float M = -1e30f;
    for (int s = 0; s < NS; s++)
      M = fmaxf(M, ML[((size_t)s * NPTS + row) * 2]);
    float L = 0.0f, a = 0.0f;
    for (int s = 0; s < NS; s++) {
      float ms = ML[((size_t)s * NPTS + row) * 2];
      float ls = ML[((size_t)s * NPTS + row) * 2 + 1];
      float wsc = fexp2(ms - M);
      L += wsc * ls;
      a = fmaf(wsc, bf2f(Opart[((size_t)s * NPTS + row) * CH + j]), a);
    }
    xs[r][j] = a / L;
  }
  __syncthreads();

  float acc[4];
  const float bj = b[j];
  #pragma unroll
  for (int r = 0; r < 4; r++) acc[r] = bj;
  for (int kk = 0; kk < CH; kk++) {
    float wv_ = W[kk * CH + j];
    #pragma unroll
    for (int r = 0; r < 4; r++) acc[r] = fmaf(xs[r][kk], wv_, acc[r]);
  }
  #pragma unroll
  for (int r = 0; r < 4; r++) acc[r] += res[(r0 + r) * CH + j];

  const int wv2 = j >> 6, ln = j & 63;
  float sum[4];
  #pragma unroll
  for (int r = 0; r < 4; r++) sum[r] = acc[r];
  #pragma unroll
  for (int o = 32; o; o >>= 1) {
    #pragma unroll
    for (int r = 0; r < 4; r++) sum[r] += __shfl_xor(sum[r], o);
  }
  if (ln == 0) {
    #pragma unroll
    for (int r = 0; r < 4; r++) red[wv2][r] = sum[r];
  }
  __syncthreads();
  float dv[4];
  #pragma unroll
  for (int r = 0; r < 4; r++) {
    float mean = (red[0][r] + red[1][r]) * (1.0f / 128.0f);
    dv[r] = acc[r] - mean;
    sum[r] = dv[r] * dv[r];
  }
  #pragma unroll
  for (int o = 32; o; o >>= 1) {
    #pragma unroll
    for (int r = 0; r < 4; r++) sum[r] += __shfl_xor(sum[r], o);
  }
  __syncthreads();
  if (ln == 0) {
    #pragma unroll
    for (int r = 0; r < 4; r++) red[wv2][r] = sum[r];
  }
  __syncthreads();
  const float gj = g[j], betaj = beta[j];
  #pragma unroll
  for (int r = 0; r < 4; r++) {
    float var = (red[0][r] + red[1][r]) * (1.0f / 128.0f);
    out[(r0 + r) * CH + j] = dv[r] * rsqrtf(var + 1e-5f) * gj + betaj;
  }
}

// ---------------------------------------------------------------------------
// Kernel 5: final row normalize + classifier MLP + sigmoid
// ---------------------------------------------------------------------------
__global__ __launch_bounds__(128) void k_final(
    const float* __restrict__ F,
    const float* __restrict__ c1W, const float* __restrict__ c1b,
    const float* __restrict__ c2W, const float* __restrict__ c2b,
    const float* __restrict__ c3W, const float* __restrict__ c3b,
    float* __restrict__ out) {
  const int row = blockIdx.x, j = threadIdx.x;
  __shared__ float xs[CH];
  __shared__ float h1[32];
  __shared__ float h2[32];
  __shared__ float red[2];
  float x = F[row * CH + j];
  float ss = x * x;
  #pragma unroll
  for (int o = 32; o; o >>= 1) ss += __shfl_xor(ss, o);
  if ((j & 63) == 0) red[j >> 6] = ss;
  __syncthreads();
  float norm = sqrtf(red[0] + red[1]);
  float xn = x / fmaxf(norm, 1e-12f);
  xs[j] = xn;
  out[row * CH + j] = xn;
  __syncthreads();
  if (j < 32) {
    float a = c1b[j];
    for (int kk = 0; kk < CH; kk++) a = fmaf(xs[kk], c1W[kk * 32 + j], a);
    h1[j] = fmaxf(a, 0.0f);
  }
  __syncthreads();
  if (j < 32) {
    float a = c2b[j];
    #pragma unroll
    for (int kk = 0; kk < 32; kk++) a = fmaf(h1[kk], c2W[kk * 32 + j], a);
    h2[j] = fmaxf(a, 0.0f);
  }
  __syncthreads();
  if (j == 0) {
    float a = c3b[0];
    #pragma unroll
    for (int kk = 0; kk < 32; kk++) a = fmaf(h2[kk], c3W[kk], a);
    out[NPTS * CH + row] = 1.0f / (1.0f + __expf(-a));
  }
}

// ---------------------------------------------------------------------------
extern "C" void kernel_launch(void* const* d_in, const int* in_sizes, int n_in,
                              void* d_out, int out_size, void* d_ws, size_t ws_size,
                              hipStream_t stream) {
  const float* refp = (const float*)d_in[0];
  const float* srcp = (const float*)d_in[1];
  const float* cf   = (const float*)d_in[2];
  const float* Win  = (const float*)d_in[3];
  const float* bin  = (const float*)d_in[4];
  const float* mlpW = (const float*)d_in[5];
  const float* mlpb = (const float*)d_in[6];
  const float* mlpg = (const float*)d_in[7];
  const float* mlpbeta = (const float*)d_in[8];
  const float* Wq = (const float*)d_in[9];
  const float* bq = (const float*)d_in[10];
  const float* Wk = (const float*)d_in[11];
  const float* bk = (const float*)d_in[12];
  const float* Wv = (const float*)d_in[13];
  const float* bv = (const float*)d_in[14];
  const float* Wo = (const float*)d_in[15];
  const float* bo = (const float*)d_in[16];
  const float* lng = (const float*)d_in[17];
  const float* lnb = (const float*)d_in[18];
  const float* c1W = (const float*)d_in[19];
  const float* c1b = (const float*)d_in[20];
  const float* c2W = (const float*)d_in[21];
  const float* c2b = (const float*)d_in[22];
  const float* c3W = (const float*)d_in[23];
  const float* c3b = (const float*)d_in[24];
  float* out = (float*)d_out;

  const size_t NC = (size_t)NPTS * CH;
  const size_t geo_bytes = (size_t)NPTS * NPTS * 2;
  const size_t seg_bytes = NC * 2 + (size_t)NPTS * 8;   // bf16 Opart + fp32 ML
  const size_t base = 2 * NC * 4 + 3 * NC * 2;

  int NS = 0;
  bool useGeo = false;
  {
    const int cands[8] = {16, 12, 8, 6, 4, 3, 2, 1};
    for (int i = 0; i < 8; i++)
      if (base + geo_bytes + (size_t)cands[i] * seg_bytes <= ws_size) {
        NS = cands[i]; useGeo = true; break;
      }
    if (!NS) {
      for (int i = 0; i < 8; i++)
        if (base + (size_t)cands[i] * seg_bytes <= ws_size) { NS = cands[i]; break; }
      if (!NS) NS = 1;
    }
  }

  char* p = (char*)d_ws;
  float* F = (float*)p;        p += NC * 4;
  float* T = (float*)p;        p += NC * 4;
  ushort* Qb = (ushort*)p;     p += NC * 2;
  ushort* Kb = (ushort*)p;     p += NC * 2;
  ushort* Vtb = (ushort*)p;    p += NC * 2;
  ushort* geo = nullptr;
  if (useGeo) { geo = (ushort*)p; p += geo_bytes; }
  ushort* Opart = (ushort*)p;  p += (size_t)NS * NC * 2;
  float* ML = (float*)p;
  const int ntiles = NPTS / 64 / NS;

  if (useGeo)
    k_geo<<<NPTS / 4, 256, 0, stream>>>(refp, srcp, geo);
  k_embed<<<NPTS, 128, 0, stream>>>(refp, srcp, cf, Win, bin, F);
  for (int i = 0; i < 3; i++) {
    const int o2 = i * CH * CH, o1 = i * CH;
    k_mlp_qkv<<<NPTS / 4, 128, 0, stream>>>(
        F, mlpW + o2, mlpb + o1, mlpg + o1, mlpbeta + o1,
        Wq + o2, bq + o1, Wk + o2, bk + o1, Wv + o2, bv + o1,
        T, Qb, Kb, Vtb);
    dim3 agrid(NPTS / 128, NS);
    if (useGeo)
      k_attn_mfma<1><<<agrid, 256, 0, stream>>>(Qb, Kb, Vtb, geo, refp, srcp,
                                                Opart, ML, ntiles);
    else
      k_attn_mfma<0><<<agrid, 256, 0, stream>>>(Qb, Kb, Vtb, nullptr, refp, srcp,
                                                Opart, ML, ntiles);
    k_out<<<NPTS / 4, 128, 0, stream>>>(Opart, ML, NS, Wo + o2, bo + o1,
                                        lng + o1, lnb + o1, T, F);
  }
  k_final<<<NPTS, 128, 0, stream>>>(F, c1W, c1b, c2W, c2b, c3W, c3b, out);
}